// Round 11
// baseline (164.653 us; speedup 1.0000x reference)
//
#include <hip/hip_runtime.h>
#include <hip/hip_fp16.h>

// Problem constants
#define IMGS 2
#define OW 90
#define NP 8100                // 90*90 valid patches
#define HW 96
#define CH_STRIDE 9216
#define IMG_STRIDE 27648
#define KP 192                 // padded row stride in halfs (data to 159; rest zero)
#define MP 8192                // padded patch count
#define ALPHA 0.05f
#define INV_D (1.0f/147.0f)
#define PAD_SENTINEL 60000.0f  // finite fp16 value >> any real distance magnitude

typedef _Float16 half8 __attribute__((ext_vector_type(8)));
typedef float floatx4 __attribute__((ext_vector_type(4)));

// async global->LDS, 16B per lane; LDS dest = uniform base + lane*16
#define GLD_LDS16(gp, lp)                                                     \
    __builtin_amdgcn_global_load_lds(                                         \
        (const __attribute__((address_space(1))) void*)(gp),                  \
        (__attribute__((address_space(3))) void*)(lp), 16, 0, 0)

// ws byte offsets
// A matrix = -2*Y, slot147 = 1.0, slot148 = y2 (valid) / 0 (pad)
// B matrix =    X, slot147 = x2 (valid) / 60000 (pad), slot148 = 1 / 0
// => A-row . B-row = x2 + y2 - 2*cross  (FULL unnormalized distance)
#define XP_OFF   0
#define YP_OFF   (XP_OFF + IMGS*MP*KP*2)
#define RMIN_OFF (YP_OFF + IMGS*MP*KP*2)        // int-bits float [2][8192]
#define CMIN_OFF (RMIN_OFF + IMGS*MP*4)
#define ACC_OFF  (CMIN_OFF + IMGS*MP*4)         // float accumulator
#define CNT_OFF  (ACC_OFF + 4)                  // completion counter

// -------- fused build + min/acc-init --------------------------------------
__global__ __launch_bounds__(256) void k_build(const float* __restrict__ x,
                                               const float* __restrict__ y,
                                               char* __restrict__ wsb) {
    int tid = threadIdx.x;
    int hwv = tid >> 5;                      // half-wave 0..7
    int l = tid & 31;
    int grow = blockIdx.x * 8 + hwv;         // 0..32767
    int tensor = grow >> 14;                 // 0 = x(B), 1 = y(A)
    int img = (grow >> 13) & 1;
    int row = grow & (MP - 1);
    const float* src = (tensor ? y : x) + img * IMG_STRIDE;
    int py = row / OW, px = row - py * OW;
    bool rvalid = row < NP;

    float vals[8];
#pragma unroll
    for (int j = 0; j < 8; j++) {
        int k = l * 8 + j;
        float v = 0.0f;
        if (rvalid && k < 147) {
            int c = k / 49;
            int rm = k - c * 49;
            int dy = rm / 7, dx = rm - dy * 7;
            v = src[c * CH_STRIDE + (py + dy) * HW + px + dx];
        }
        vals[j] = (float)(_Float16)v;        // round through fp16 (ref casts first)
    }
    float ss16 = 0.0f;                       // squared norm of fp16-rounded row
#pragma unroll
    for (int j = 0; j < 8; j++) ss16 = fmaf(vals[j], vals[j], ss16);
#pragma unroll
    for (int m = 1; m < 32; m <<= 1) ss16 += __shfl_xor(ss16, m, 32);

    half8 h;
#pragma unroll
    for (int j = 0; j < 8; j++) {
        float f = vals[j];
        if (tensor) f *= -2.0f;              // A = -2*Y (exact in fp16)
        h[j] = (_Float16)f;
    }
    if (l == 18) {                           // k=147 is j=3, k=148 is j=4
        if (tensor) {                        // A (Y): slot147=1, slot148=y2
            h[3] = (_Float16)1.0f;
            h[4] = rvalid ? (_Float16)ss16 : (_Float16)0.0f;
        } else {                             // B (X): slot147=x2/sentinel, 148=1/0
            h[3] = rvalid ? (_Float16)ss16 : (_Float16)PAD_SENTINEL;
            h[4] = rvalid ? (_Float16)1.0f : (_Float16)0.0f;
        }
    }
    if (l < 24) {
        _Float16* dst = (_Float16*)(wsb + (tensor ? YP_OFF : XP_OFF)) +
                        ((size_t)img * MP + row) * KP + l * 8;
        *(half8*)dst = h;
    }
    if (tid < 8) {                           // min-array init (ws is re-poisoned)
        int gi = blockIdx.x * 8 + tid;
        if (gi < IMGS * MP)
            ((int*)(wsb + RMIN_OFF))[gi] = 0x7f800000;
        else
            ((int*)(wsb + CMIN_OFF))[gi - IMGS * MP] = 0x7f800000;
    }
    if (blockIdx.x == 0 && tid == 0) {
        *(float*)(wsb + ACC_OFF) = 0.0f;
        *(int*)(wsb + CNT_OFF) = 0;
    }
}

// -------- resident-operand streaming GEMM (r9 skeleton, unified folds) ----
// 2x20KB double buffer + 4KB RM slice -> 3 blocks/CU (launch_bounds(256,3),
// 12 waves/CU). Resident 128 rows: rf[4][5] per wave (w>>1 picks half).
// Streamed 64-row tiles: sf0/sf1 per ks (w&1 picks half). Both passes:
//   acc = mfma(sf, rf[i], acc)  -> C rows = streamed, C cols = resident;
//   min folds over streamed (regs + quads), one atomicMin per resident col.
// PASS 1: resident Y, stream X: acc = x2+y2-2c -> RMIN (full distance).
// PASS 2: resident X, stream Y scaled on the fly by r' = INV_D/(rm*INV_D+a)
//   (rm from LDS-prefetched slice): acc = r'(x2+y2-2c) -> CMIN.
//   Pad streamed rows: r'=0 zeroes row; sentinel re-injected at k=148.
#define R2OFF 8192   // halfs: region2 base within a 10240-half buffer

#define STAGE64(mat, buf)                                                      \
    {                                                                          \
        int rb_ = w * 16;                                                      \
        _Pragma("unroll") for (int g_ = 0; g_ < 4; g_++) {                     \
            int r_ = rb_ + g_ * 4 + (lane >> 4);                               \
            int gc_ = (lane & 15) ^ (r_ & 7);                                  \
            GLD_LDS16((mat) + (size_t)r_ * KP + gc_ * 8,                       \
                      (buf) + (rb_ + g_ * 4) * 128);                           \
        }                                                                      \
        int r2_ = rb_ + (lane >> 2);                                           \
        int gc2_ = (lane & 3) ^ ((r2_ >> 1) & 3);                              \
        GLD_LDS16((mat) + (size_t)r2_ * KP + 128 + gc2_ * 8,                   \
                  (buf) + R2OFF + rb_ * 32);                                   \
    }

#define READFRAG(buf, row, ks)                                                 \
    ((ks) < 4 ? *(const half8*)(&(buf)[(row) * 128 +                           \
                                       ((((ks) * 4 + quad) ^ ((row) & 7)) * 8)]) \
              : *(const half8*)(&(buf)[R2OFF + (row) * 32 +                    \
                                       ((quad ^ (((row) >> 1) & 3)) * 8)]))

template <int PASS>
__global__ __launch_bounds__(256, 3) void k_gemm(char* __restrict__ wsb) {
    __shared__ __align__(16) _Float16 Buf[2][10240];   // 2 x 20 KB
    __shared__ __align__(16) int RMl[1024];            // PASS2: rmin bits, q's rows
    int tid = threadIdx.x;
    int lane = tid & 63, w = tid >> 6;
    int quad = lane >> 4, col16 = lane & 15;
    int q = blockIdx.x;                      // octant: 16 streamed 64-row tiles
    int rtile = blockIdx.y;                  // resident 128-row tile
    int img = blockIdx.z;

    const _Float16* Res = (const _Float16*)(wsb + (PASS == 1 ? YP_OFF : XP_OFF)) +
                          ((size_t)img * MP + rtile * 128) * KP;
    const _Float16* Str = (const _Float16*)(wsb + (PASS == 1 ? XP_OFF : YP_OFF)) +
                          (size_t)img * MP * KP;

    // ---- prologue: resident 128 rows -> both buffers; PASS2: RM slice ----
    STAGE64(Res, Buf[0]);
    STAGE64(Res + (size_t)64 * KP, Buf[1]);
    if (PASS == 2 && w == 0) {
        const char* RMg = wsb + RMIN_OFF + ((size_t)img * MP + q * 1024) * 4;
#pragma unroll
        for (int g = 0; g < 4; g++)
            GLD_LDS16(RMg + g * 1024 + lane * 16, &RMl[g * 256]);
    }
    __syncthreads();
    half8 rf[4][5];                          // waves 0,1: resident rows 0..63;
    const _Float16* rb = Buf[w >> 1];        // waves 2,3: rows 64..127
#pragma unroll
    for (int i = 0; i < 4; i++)
#pragma unroll
        for (int c = 0; c < 5; c++)
            rf[i][c] = READFRAG(rb, i * 16 + col16, c);
    __syncthreads();                         // rf reads drained before overwrite
    STAGE64(Str + (size_t)(q * 16) * 64 * KP, Buf[0]);   // tile 0 -> buf0

    float mn[4];
#pragma unroll
    for (int i = 0; i < 4; i++) mn[i] = 1e30f;
    int s0 = (w & 1) * 32;                   // wave's streamed half

    for (int s = 0; s < 16; s++) {
        __syncthreads();                     // drains prefetch of s; reads of s-1 done
        if (s < 15)
            STAGE64(Str + (size_t)(q * 16 + s + 1) * 64 * KP, Buf[(s + 1) & 1]);
        const _Float16* sb = Buf[s & 1];

        _Float16 rp0 = (_Float16)1.0f, rp1 = (_Float16)1.0f;
        bool pad0 = false, pad1 = false;
        if (PASS == 2) {                     // r' from the LDS slice (no global)
            int b0 = RMl[s * 64 + s0 + col16];
            int b1 = RMl[s * 64 + s0 + 16 + col16];
            pad0 = (b0 == 0x7f800000);
            pad1 = (b1 == 0x7f800000);
            rp0 = (_Float16)(INV_D / (__int_as_float(b0) * INV_D + ALPHA));
            rp1 = (_Float16)(INV_D / (__int_as_float(b1) * INV_D + ALPHA));
        }

        floatx4 acc[8];
#pragma unroll
        for (int i = 0; i < 8; i++) acc[i] = (floatx4){0.f, 0.f, 0.f, 0.f};
#pragma unroll
        for (int ks = 0; ks < 5; ks++) {
            half8 sf0 = READFRAG(sb, s0 + col16, ks);
            half8 sf1 = READFRAG(sb, s0 + 16 + col16, ks);
            if (PASS == 2) {
                half8 v0 = {rp0, rp0, rp0, rp0, rp0, rp0, rp0, rp0};
                half8 v1 = {rp1, rp1, rp1, rp1, rp1, rp1, rp1, rp1};
                sf0 = sf0 * v0;              // v_pk_mul_f16
                sf1 = sf1 * v1;
                if (ks == 4 && quad == 2) {  // k=148 sits at quad2, j=4
                    if (pad0) sf0[4] = (_Float16)PAD_SENTINEL;
                    if (pad1) sf1[4] = (_Float16)PAD_SENTINEL;
                }
            }
#pragma unroll
            for (int i = 0; i < 4; i++) {
                acc[i] = __builtin_amdgcn_mfma_f32_16x16x32_f16(
                    sf0, rf[i][ks], acc[i], 0, 0, 0);
                acc[4 + i] = __builtin_amdgcn_mfma_f32_16x16x32_f16(
                    sf1, rf[i][ks], acc[4 + i], 0, 0, 0);
            }
        }
        // fold over streamed rows held in regs (pads auto-masked by sentinels)
#pragma unroll
        for (int i = 0; i < 4; i++) {
            float a = fminf(fminf(acc[i][0], acc[i][1]),
                            fminf(acc[i][2], acc[i][3]));
            float b = fminf(fminf(acc[4 + i][0], acc[4 + i][1]),
                            fminf(acc[4 + i][2], acc[4 + i][3]));
            mn[i] = fminf(mn[i], fminf(a, b));
        }
    }

    // ---- final: min across quads (streamed) + one atomicMin per resident col
    int* dst = (int*)(wsb + (PASS == 1 ? RMIN_OFF : CMIN_OFF)) + img * MP;
#pragma unroll
    for (int i = 0; i < 4; i++) {
        float best = mn[i];
        best = fminf(best, __shfl_xor(best, 16, 64));
        best = fminf(best, __shfl_xor(best, 32, 64));
        int cg = rtile * 128 + (w >> 1) * 64 + i * 16 + col16;
        if (quad == 0 && cg < NP)
            atomicMin(dst + cg, __float_as_int(best));
    }
}

// -------- finalize: 32 blocks, device-scope accumulate, last block writes --
__global__ __launch_bounds__(256) void k_final(char* __restrict__ wsb,
                                               float* __restrict__ out) {
    __shared__ float red[4];
    int tid = threadIdx.x;
    int gid = blockIdx.x * 256 + tid;        // 0..8191
    const int* cm = (const int*)(wsb + CMIN_OFF);
    float s = 0.0f;
    if (gid < NP)
        s = __int_as_float(cm[gid]) + __int_as_float(cm[MP + gid]);
#pragma unroll
    for (int m = 1; m < 64; m <<= 1) s += __shfl_xor(s, m, 64);
    if ((tid & 63) == 0) red[tid >> 6] = s;
    __syncthreads();
    if (tid == 0) {
        float bs = red[0] + red[1] + red[2] + red[3];
        float* acc = (float*)(wsb + ACC_OFF);
        int* cnt = (int*)(wsb + CNT_OFF);
        atomicAdd(acc, bs);
        __threadfence();
        if (atomicAdd(cnt, 1) == 31) {
            float total = atomicAdd(acc, 0.0f);   // atomic read after all adds
            out[0] = total * (0.5f / NP);
        }
    }
}

extern "C" void kernel_launch(void* const* d_in, const int* in_sizes, int n_in,
                              void* d_out, int out_size, void* d_ws, size_t ws_size,
                              hipStream_t stream) {
    const float* x = (const float*)d_in[0];
    const float* y = (const float*)d_in[1];
    char* wsb = (char*)d_ws;
    float* out = (float*)d_out;

    k_build<<<4096, 256, 0, stream>>>(x, y, wsb);
    k_gemm<1><<<dim3(8, 64, IMGS), 256, 0, stream>>>(wsb);
    k_gemm<2><<<dim3(8, 64, IMGS), 256, 0, stream>>>(wsb);
    k_final<<<32, 256, 0, stream>>>(wsb, out);
}

// Round 12
// 156.150 us; speedup vs baseline: 1.0545x; 1.0545x over previous
//
#include <hip/hip_runtime.h>
#include <hip/hip_fp16.h>

// Problem constants
#define IMGS 2
#define OW 90
#define NP 8100                // 90*90 valid patches
#define HW 96
#define CH_STRIDE 9216
#define IMG_STRIDE 27648
#define KP 192                 // padded row stride in halfs (data to 159; rest zero)
#define MP 8192                // padded patch count
#define ALPHA 0.05f
#define INV_D (1.0f/147.0f)
#define PAD_SENTINEL 60000.0f  // finite fp16 value >> any real distance magnitude

typedef _Float16 half8 __attribute__((ext_vector_type(8)));
typedef float floatx4 __attribute__((ext_vector_type(4)));

// async global->LDS, 16B per lane; LDS dest = uniform base + lane*16
#define GLD_LDS16(gp, lp)                                                     \
    __builtin_amdgcn_global_load_lds(                                         \
        (const __attribute__((address_space(1))) void*)(gp),                  \
        (__attribute__((address_space(3))) void*)(lp), 16, 0, 0)

// ws byte offsets
// A matrix = -2*Y, slot147 = 1.0, slot148 = y2 (valid) / 0 (pad)
// B matrix =    X, slot147 = x2 (valid) / 60000 (pad), slot148 = 1 / 0
// => A-row . B-row = x2 + y2 - 2*cross  (FULL unnormalized distance)
#define XP_OFF   0
#define YP_OFF   (XP_OFF + IMGS*MP*KP*2)
#define RMIN_OFF (YP_OFF + IMGS*MP*KP*2)        // int-bits float [2][8192]
#define CMIN_OFF (RMIN_OFF + IMGS*MP*4)         // contiguous after RMIN
#define ACC_OFF  (CMIN_OFF + IMGS*MP*4)         // float accumulator
#define CNT_OFF  (ACC_OFF + 4)                  // completion counter

// -------- build: 360 image-staging blocks + 4 pad/init blocks -------------
// Block b<360 = (tensor, img, py): stage image rows py..py+6 (3ch x 96) into
// LDS coalesced, compute the 90 patch-row norms from fp16-rounded values,
// then emit 90 patch rows (24 half8 chunks each) with slots 147/148 baked.
__global__ __launch_bounds__(256) void k_build(const float* __restrict__ x,
                                               const float* __restrict__ y,
                                               char* __restrict__ wsb) {
    __shared__ float I[2016];                // [c][dy][u] = c*672 + dy*96 + u
    __shared__ float nrm[90];
    int tid = threadIdx.x;
    int b = blockIdx.x;
    if (b < 360) {
        int tensor = b / 180;                // 0 = x(B), 1 = y(A)
        int img = (b / 90) % 2;
        int py = b % 90;
        const float* src = (tensor ? y : x) + img * IMG_STRIDE;
        for (int idx = tid; idx < 2016; idx += 256) {
            int c = idx / 672, rem = idx % 672;
            int dy = rem / 96, u = rem % 96;
            I[idx] = src[c * CH_STRIDE + (py + dy) * HW + u];
        }
        __syncthreads();
        if (tid < 90) {                      // norm of fp16-rounded patch row
            float s = 0.0f;
            for (int c = 0; c < 3; c++)
#pragma unroll
                for (int dy = 0; dy < 7; dy++) {
                    const float* rowp = &I[c * 672 + dy * 96 + tid];
#pragma unroll
                    for (int dx = 0; dx < 7; dx++) {
                        float v = (float)(_Float16)rowp[dx];
                        s = fmaf(v, v, s);
                    }
                }
            nrm[tid] = s;
        }
        __syncthreads();
        _Float16* dstbase = (_Float16*)(wsb + (tensor ? YP_OFF : XP_OFF)) +
                            ((size_t)img * MP + (size_t)py * 90) * KP;
        for (int ch = tid; ch < 2160; ch += 256) {   // 90 rows x 24 chunks
            int px = ch / 24, chunk = ch % 24;
            half8 h;
#pragma unroll
            for (int j = 0; j < 8; j++) {
                int k = chunk * 8 + j;
                float f = 0.0f;
                if (k < 147) {
                    int c = k / 49, rm = k - c * 49;
                    int dy = rm / 7, dx = rm - dy * 7;
                    float v = (float)(_Float16)I[c * 672 + dy * 96 + px + dx];
                    f = tensor ? -2.0f * v : v;      // A = -2*Y (exact)
                }
                h[j] = (_Float16)f;
            }
            if (chunk == 18) {               // k=147 -> j=3, k=148 -> j=4
                float ss = nrm[px];
                if (tensor) { h[3] = (_Float16)1.0f; h[4] = (_Float16)ss; }
                else        { h[3] = (_Float16)ss;   h[4] = (_Float16)1.0f; }
            }
            *(half8*)(dstbase + (size_t)px * KP + chunk * 8) = h;
        }
    } else {
        // pad rows NP..MP-1 for one (tensor,img) + min-array init slice
        int bi = b - 360;                    // 0..3
        int tensor = bi >> 1, img = bi & 1;
        _Float16* dstbase = (_Float16*)(wsb + (tensor ? YP_OFF : XP_OFF)) +
                            (size_t)img * MP * KP;
        for (int ch = tid; ch < (MP - NP) * 24; ch += 256) {
            int row = NP + ch / 24, chunk = ch % 24;
            half8 h;
#pragma unroll
            for (int j = 0; j < 8; j++) h[j] = (_Float16)0.0f;
            if (chunk == 18) {
                if (tensor) h[3] = (_Float16)1.0f;              // A pad
                else        h[3] = (_Float16)PAD_SENTINEL;      // B pad
            }
            *(half8*)(dstbase + (size_t)row * KP + chunk * 8) = h;
        }
        int* mins = (int*)(wsb + RMIN_OFF);  // RMIN+CMIN contiguous, 32768 ints
        for (int gi = bi * 8192 + tid; gi < bi * 8192 + 8192; gi += 256)
            mins[gi] = 0x7f800000;
        if (bi == 0 && tid == 0) {
            *(float*)(wsb + ACC_OFF) = 0.0f;
            *(int*)(wsb + CNT_OFF) = 0;
        }
    }
}

// -------- resident-operand streaming GEMM (r9 skeleton, 40960B LDS) -------
// LDS = EXACTLY 2x20KB = 40960B -> 4 blocks/CU (the occupancy cliff; nothing
// else may touch LDS here). Resident 128 rows: rf[4][5] per wave (w>>1 picks
// half). Streamed 64-row tiles: sf0/sf1 per ks (w&1 picks half). Both passes:
//   acc = mfma(sf, rf[i], acc) -> C rows = streamed, C cols = resident;
//   fold over streamed in regs+quads, one atomicMin per resident col.
// PASS 1: resident Y, stream X: acc = x2+y2-2c -> RMIN (full distance).
// PASS 2: resident X, stream Y scaled on the fly by r' = INV_D/(rm*INV_D+a);
//   rm bits arrive via 2 register global loads/lane prefetched ONE STEP
//   AHEAD (RMIN is 64KB, L2-resident -> latency hidden under the step).
//   Pad streamed rows: r'=0 zeroes row; sentinel re-injected at k=148.
#define R2OFF 8192   // halfs: region2 base within a 10240-half buffer

#define STAGE64(mat, buf)                                                      \
    {                                                                          \
        int rb_ = w * 16;                                                      \
        _Pragma("unroll") for (int g_ = 0; g_ < 4; g_++) {                     \
            int r_ = rb_ + g_ * 4 + (lane >> 4);                               \
            int gc_ = (lane & 15) ^ (r_ & 7);                                  \
            GLD_LDS16((mat) + (size_t)r_ * KP + gc_ * 8,                       \
                      (buf) + (rb_ + g_ * 4) * 128);                           \
        }                                                                      \
        int r2_ = rb_ + (lane >> 2);                                           \
        int gc2_ = (lane & 3) ^ ((r2_ >> 1) & 3);                              \
        GLD_LDS16((mat) + (size_t)r2_ * KP + 128 + gc2_ * 8,                   \
                  (buf) + R2OFF + rb_ * 32);                                   \
    }

#define READFRAG(buf, row, ks)                                                 \
    ((ks) < 4 ? *(const half8*)(&(buf)[(row) * 128 +                           \
                                       ((((ks) * 4 + quad) ^ ((row) & 7)) * 8)]) \
              : *(const half8*)(&(buf)[R2OFF + (row) * 32 +                    \
                                       ((quad ^ (((row) >> 1) & 3)) * 8)]))

template <int PASS>
__global__ __launch_bounds__(256, 3) void k_gemm(char* __restrict__ wsb) {
    __shared__ __align__(16) _Float16 Buf[2][10240];   // 2 x 20 KB — NOTHING MORE
    int tid = threadIdx.x;
    int lane = tid & 63, w = tid >> 6;
    int quad = lane >> 4, col16 = lane & 15;
    int q = blockIdx.x;                      // octant: 16 streamed 64-row tiles
    int rtile = blockIdx.y;                  // resident 128-row tile
    int img = blockIdx.z;

    const _Float16* Res = (const _Float16*)(wsb + (PASS == 1 ? YP_OFF : XP_OFF)) +
                          ((size_t)img * MP + rtile * 128) * KP;
    const _Float16* Str = (const _Float16*)(wsb + (PASS == 1 ? XP_OFF : YP_OFF)) +
                          (size_t)img * MP * KP;
    const int* RM = (const int*)(wsb + RMIN_OFF) + img * MP;

    // ---- prologue: resident 128 rows -> both buffers -> registers ----
    STAGE64(Res, Buf[0]);
    STAGE64(Res + (size_t)64 * KP, Buf[1]);
    __syncthreads();
    half8 rf[4][5];                          // waves 0,1: resident rows 0..63;
    const _Float16* rb = Buf[w >> 1];        // waves 2,3: rows 64..127
#pragma unroll
    for (int i = 0; i < 4; i++)
#pragma unroll
        for (int c = 0; c < 5; c++)
            rf[i][c] = READFRAG(rb, i * 16 + col16, c);
    __syncthreads();                         // rf reads drained before overwrite
    STAGE64(Str + (size_t)(q * 16) * 64 * KP, Buf[0]);   // tile 0 -> buf0

    float mn[4];
#pragma unroll
    for (int i = 0; i < 4; i++) mn[i] = 1e30f;
    int s0 = (w & 1) * 32;                   // wave's streamed half

    int cb0 = 0, cb1 = 0;                    // current-step rmin bits (PASS 2)
    if (PASS == 2) {
        cb0 = RM[(q * 16) * 64 + s0 + col16];
        cb1 = RM[(q * 16) * 64 + s0 + 16 + col16];
    }

    for (int s = 0; s < 16; s++) {
        __syncthreads();                     // drains prefetch of s; reads of s-1 done
        if (s < 15)
            STAGE64(Str + (size_t)(q * 16 + s + 1) * 64 * KP, Buf[(s + 1) & 1]);
        int nb0 = 0, nb1 = 0;
        if (PASS == 2 && s < 15) {           // prefetch next step's rmin bits
            nb0 = RM[(q * 16 + s + 1) * 64 + s0 + col16];
            nb1 = RM[(q * 16 + s + 1) * 64 + s0 + 16 + col16];
        }
        const _Float16* sb = Buf[s & 1];

        _Float16 rp0 = (_Float16)1.0f, rp1 = (_Float16)1.0f;
        bool pad0 = false, pad1 = false;
        if (PASS == 2) {
            pad0 = (cb0 == 0x7f800000);
            pad1 = (cb1 == 0x7f800000);
            rp0 = (_Float16)(INV_D / (__int_as_float(cb0) * INV_D + ALPHA));
            rp1 = (_Float16)(INV_D / (__int_as_float(cb1) * INV_D + ALPHA));
        }

        floatx4 acc[8];
#pragma unroll
        for (int i = 0; i < 8; i++) acc[i] = (floatx4){0.f, 0.f, 0.f, 0.f};
#pragma unroll
        for (int ks = 0; ks < 5; ks++) {
            half8 sf0 = READFRAG(sb, s0 + col16, ks);
            half8 sf1 = READFRAG(sb, s0 + 16 + col16, ks);
            if (PASS == 2) {
                half8 v0 = {rp0, rp0, rp0, rp0, rp0, rp0, rp0, rp0};
                half8 v1 = {rp1, rp1, rp1, rp1, rp1, rp1, rp1, rp1};
                sf0 = sf0 * v0;              // v_pk_mul_f16
                sf1 = sf1 * v1;
                if (ks == 4 && quad == 2) {  // k=148 sits at quad2, j=4
                    if (pad0) sf0[4] = (_Float16)PAD_SENTINEL;
                    if (pad1) sf1[4] = (_Float16)PAD_SENTINEL;
                }
            }
#pragma unroll
            for (int i = 0; i < 4; i++) {
                acc[i] = __builtin_amdgcn_mfma_f32_16x16x32_f16(
                    sf0, rf[i][ks], acc[i], 0, 0, 0);
                acc[4 + i] = __builtin_amdgcn_mfma_f32_16x16x32_f16(
                    sf1, rf[i][ks], acc[4 + i], 0, 0, 0);
            }
        }
        // fold over streamed rows held in regs (pads auto-masked by sentinels)
#pragma unroll
        for (int i = 0; i < 4; i++) {
            float a = fminf(fminf(acc[i][0], acc[i][1]),
                            fminf(acc[i][2], acc[i][3]));
            float bmin = fminf(fminf(acc[4 + i][0], acc[4 + i][1]),
                               fminf(acc[4 + i][2], acc[4 + i][3]));
            mn[i] = fminf(mn[i], fminf(a, bmin));
        }
        if (PASS == 2 && s < 15) { cb0 = nb0; cb1 = nb1; }
    }

    // ---- final: min across quads (streamed) + one atomicMin per resident col
    int* dst = (int*)(wsb + (PASS == 1 ? RMIN_OFF : CMIN_OFF)) + img * MP;
#pragma unroll
    for (int i = 0; i < 4; i++) {
        float best = mn[i];
        best = fminf(best, __shfl_xor(best, 16, 64));
        best = fminf(best, __shfl_xor(best, 32, 64));
        int cg = rtile * 128 + (w >> 1) * 64 + i * 16 + col16;
        if (quad == 0 && cg < NP)
            atomicMin(dst + cg, __float_as_int(best));
    }
}

// -------- finalize: 32 blocks, device-scope accumulate, last block writes --
__global__ __launch_bounds__(256) void k_final(char* __restrict__ wsb,
                                               float* __restrict__ out) {
    __shared__ float red[4];
    int tid = threadIdx.x;
    int gid = blockIdx.x * 256 + tid;        // 0..8191
    const int* cm = (const int*)(wsb + CMIN_OFF);
    float s = 0.0f;
    if (gid < NP)
        s = __int_as_float(cm[gid]) + __int_as_float(cm[MP + gid]);
#pragma unroll
    for (int m = 1; m < 64; m <<= 1) s += __shfl_xor(s, m, 64);
    if ((tid & 63) == 0) red[tid >> 6] = s;
    __syncthreads();
    if (tid == 0) {
        float bs = red[0] + red[1] + red[2] + red[3];
        float* acc = (float*)(wsb + ACC_OFF);
        int* cnt = (int*)(wsb + CNT_OFF);
        atomicAdd(acc, bs);
        __threadfence();
        if (atomicAdd(cnt, 1) == 31) {
            float total = atomicAdd(acc, 0.0f);   // atomic read after all adds
            out[0] = total * (0.5f / NP);
        }
    }
}

extern "C" void kernel_launch(void* const* d_in, const int* in_sizes, int n_in,
                              void* d_out, int out_size, void* d_ws, size_t ws_size,
                              hipStream_t stream) {
    const float* x = (const float*)d_in[0];
    const float* y = (const float*)d_in[1];
    char* wsb = (char*)d_ws;
    float* out = (float*)d_out;

    k_build<<<364, 256, 0, stream>>>(x, y, wsb);
    k_gemm<1><<<dim3(8, 64, IMGS), 256, 0, stream>>>(wsb);
    k_gemm<2><<<dim3(8, 64, IMGS), 256, 0, stream>>>(wsb);
    k_final<<<32, 256, 0, stream>>>(wsb, out);
}